// Round 7
// baseline (102.961 us; speedup 1.0000x reference)
//
#include <hip/hip_runtime.h>
#include <hip/hip_bf16.h>

// Outputs (flat in d_out, all read back as float32 by the harness):
//   messages : [B, M, D] f32
//   upd_nodes: [B, M]    (int32 ref -> store as float values; -1.0f pad)
//   upd_ts   : [B, M]    f32
//
// R4 structure (best: 96.0 us), single change: message-stream stores are
// PLAIN float4 (write-back path, like the 6.7 TB/s fillBuffer) instead of
// nontemporal. Everything else byte-identical to R4.

typedef float f32x4 __attribute__((ext_vector_type(4)));

constexpr int Dc = 256;   // message dim (harness-fixed)
constexpr int Mc = 128;   // max members (harness-fixed)

__global__ __launch_bounds__(256) void topk_main_spec(
    const float* __restrict__ unique_message,   // [B, 256]
    const float* __restrict__ member_score,     // [N_COMM, 128]
    const float* __restrict__ timestamps,       // [B]
    const int*   __restrict__ nodes,            // [B]
    const int*   __restrict__ node2community,   // [N_NODES]
    const int*   __restrict__ community2node,   // [N_COMM, 128]
    const int*   __restrict__ member_num,       // [N_COMM]
    const int*   __restrict__ community_index,  // [n_active]
    int n_active,
    float* __restrict__ out_msgs,               // [B, 128, 256]
    float* __restrict__ out_nodes,              // [B, 128] (float-encoded)
    float* __restrict__ out_ts)                 // [B, 128]
{
    const int b    = blockIdx.x;
    const int tid  = threadIdx.x;
    const int lane = tid & 63;
    const int r    = tid >> 6;        // wave id 0..3

    __shared__ float s_score[Mc];

    // 1. Message float4 — no dependence on the cid chain, issue first.
    const f32x4 m4 = reinterpret_cast<const f32x4*>(
        unique_message + (size_t)b * Dc)[lane];

    // 2. Scalar preamble (3-deep dependent chain, L2-hit).
    const int   cid  = node2community[nodes[b]];
    const int   mnum = member_num[cid];
    const float tsb  = timestamps[b];

    // 3a. Stage score row into LDS (512 B, coalesced).
    if (tid < Mc) s_score[tid] = member_score[(size_t)cid * Mc + tid];

    // 3b. Per-wave membership scan (L2-resident, ~24 loads/lane, no barrier).
    bool f = false;
    for (int i = lane; i < n_active; i += 64)
        f |= (community_index[i] == cid);
    const bool use = __any(f);
    const int  mlim = use ? mnum : 0;   // single-compare validity bound

    // Side outputs (waves 0-1): one thread per member slot, 512 B coalesced.
    if (tid < Mc) {
        const bool valid = tid < mlim;
        const float vn = valid ? (float)community2node[(size_t)cid * Mc + tid]
                               : -1.0f;
        __builtin_nontemporal_store(vn,  &out_nodes[(size_t)b * Mc + tid]);
        __builtin_nontemporal_store(valid ? tsb : 0.0f,
                                    &out_ts[(size_t)b * Mc + tid]);
    }

    __syncthreads();  // 4. scores visible

    // 5. Each wave streams a contiguous 32-row (32 KB) quarter — PLAIN stores.
    f32x4* __restrict__ outm = reinterpret_cast<f32x4*>(
        out_msgs + (size_t)b * Mc * Dc) + (size_t)r * (32 * 64) + lane;

    const int m0 = r * 32;
#pragma unroll
    for (int k = 0; k < 32; ++k) {
        const int m = m0 + k;
        const float s = (m < mlim) ? s_score[m] : 0.0f;  // LDS broadcast read
        f32x4 o;
        o.x = s * m4.x; o.y = s * m4.y; o.z = s * m4.z; o.w = s * m4.w;
        outm[(size_t)k * 64] = o;
    }
}

extern "C" void kernel_launch(void* const* d_in, const int* in_sizes, int n_in,
                              void* d_out, int out_size, void* d_ws, size_t ws_size,
                              hipStream_t stream) {
    const float* unique_message  = (const float*)d_in[0];
    const float* member_score    = (const float*)d_in[1];
    const float* timestamps      = (const float*)d_in[2];
    const int*   nodes           = (const int*)d_in[3];
    const int*   node2community  = (const int*)d_in[4];
    const int*   community2node  = (const int*)d_in[5];
    const int*   member_num      = (const int*)d_in[6];
    const int*   community_index = (const int*)d_in[7];

    const int B        = in_sizes[2];
    const int N_COMM   = in_sizes[6];
    const int M        = in_sizes[1] / N_COMM;
    const int D        = in_sizes[0] / B;
    const int N_ACTIVE = in_sizes[7];

    float* out_msgs  = (float*)d_out;
    float* out_nodes = out_msgs + (size_t)B * M * D;
    float* out_ts    = out_nodes + (size_t)B * M;

    (void)d_ws; (void)ws_size; (void)n_in; (void)out_size; (void)M; (void)D;

    topk_main_spec<<<B, 256, 0, stream>>>(
        unique_message, member_score, timestamps, nodes,
        node2community, community2node, member_num,
        community_index, N_ACTIVE,
        out_msgs, out_nodes, out_ts);
}

// Round 8
// 95.717 us; speedup vs baseline: 1.0757x; 1.0757x over previous
//
#include <hip/hip_runtime.h>
#include <hip/hip_bf16.h>

// FINAL (R4 structure, best measured: 96.0 us ~ 5.8 TB/s effective).
//
// Outputs (flat in d_out, all read back as float32 by the harness):
//   messages : [B, M, D] f32
//   upd_nodes: [B, M]    (int32 ref -> store as float values; -1.0f pad)
//   upd_ts   : [B, M]    f32
//
// One block per event. Structure (single barrier, LDS score broadcast):
//   1. issue message float4 load (independent of the cid chain)
//   2. scalar preamble: cid = node2community[nodes[b]], mnum, ts
//   3. stage member_score row (512 B) into LDS  (tid < 128)
//      + per-wave membership scan of community_index (L2-resident) -> __any
//   4. one __syncthreads()
//   5. stream the [128, 256] outer-product tile, NONTEMPORAL float4 stores
//      (nt beats plain by ~7 us: avoids L2 allocation churn), each wave a
//      contiguous 32 KB quarter; score via LDS broadcast read (free).
//
// Proven-null/negative alternatives (do not revisit): register/readlane score
// paths, barrier elimination, persistent-block preamble pipelining, plain
// stores. Preamble latency is fully hidden by 8-blocks/CU TLP.

typedef float f32x4 __attribute__((ext_vector_type(4)));

constexpr int Dc = 256;   // message dim (harness-fixed)
constexpr int Mc = 128;   // max members (harness-fixed)

__global__ __launch_bounds__(256) void topk_main_spec(
    const float* __restrict__ unique_message,   // [B, 256]
    const float* __restrict__ member_score,     // [N_COMM, 128]
    const float* __restrict__ timestamps,       // [B]
    const int*   __restrict__ nodes,            // [B]
    const int*   __restrict__ node2community,   // [N_NODES]
    const int*   __restrict__ community2node,   // [N_COMM, 128]
    const int*   __restrict__ member_num,       // [N_COMM]
    const int*   __restrict__ community_index,  // [n_active]
    int n_active,
    float* __restrict__ out_msgs,               // [B, 128, 256]
    float* __restrict__ out_nodes,              // [B, 128] (float-encoded)
    float* __restrict__ out_ts)                 // [B, 128]
{
    const int b    = blockIdx.x;
    const int tid  = threadIdx.x;
    const int lane = tid & 63;
    const int r    = tid >> 6;        // wave id 0..3

    __shared__ float s_score[Mc];

    // 1. Message float4 — no dependence on the cid chain, issue first.
    const f32x4 m4 = reinterpret_cast<const f32x4*>(
        unique_message + (size_t)b * Dc)[lane];

    // 2. Scalar preamble (3-deep dependent chain, L2-hit).
    const int   cid  = node2community[nodes[b]];
    const int   mnum = member_num[cid];
    const float tsb  = timestamps[b];

    // 3a. Stage score row into LDS (512 B, coalesced).
    if (tid < Mc) s_score[tid] = member_score[(size_t)cid * Mc + tid];

    // 3b. Per-wave membership scan (L2-resident, ~24 loads/lane, no barrier).
    bool f = false;
    for (int i = lane; i < n_active; i += 64)
        f |= (community_index[i] == cid);
    const bool use = __any(f);
    const int  mlim = use ? mnum : 0;   // single-compare validity bound

    // Side outputs (waves 0-1): one thread per member slot, 512 B coalesced.
    if (tid < Mc) {
        const bool valid = tid < mlim;
        const float vn = valid ? (float)community2node[(size_t)cid * Mc + tid]
                               : -1.0f;
        __builtin_nontemporal_store(vn,  &out_nodes[(size_t)b * Mc + tid]);
        __builtin_nontemporal_store(valid ? tsb : 0.0f,
                                    &out_ts[(size_t)b * Mc + tid]);
    }

    __syncthreads();  // 4. scores visible

    // 5. Each wave streams a contiguous 32-row (32 KB) quarter.
    f32x4* __restrict__ outm = reinterpret_cast<f32x4*>(
        out_msgs + (size_t)b * Mc * Dc) + (size_t)r * (32 * 64) + lane;

    const int m0 = r * 32;
#pragma unroll
    for (int k = 0; k < 32; ++k) {
        const int m = m0 + k;
        const float s = (m < mlim) ? s_score[m] : 0.0f;  // LDS broadcast read
        f32x4 o;
        o.x = s * m4.x; o.y = s * m4.y; o.z = s * m4.z; o.w = s * m4.w;
        __builtin_nontemporal_store(o, outm + (size_t)k * 64);
    }
}

extern "C" void kernel_launch(void* const* d_in, const int* in_sizes, int n_in,
                              void* d_out, int out_size, void* d_ws, size_t ws_size,
                              hipStream_t stream) {
    const float* unique_message  = (const float*)d_in[0];
    const float* member_score    = (const float*)d_in[1];
    const float* timestamps      = (const float*)d_in[2];
    const int*   nodes           = (const int*)d_in[3];
    const int*   node2community  = (const int*)d_in[4];
    const int*   community2node  = (const int*)d_in[5];
    const int*   member_num      = (const int*)d_in[6];
    const int*   community_index = (const int*)d_in[7];

    const int B        = in_sizes[2];
    const int N_COMM   = in_sizes[6];
    const int M        = in_sizes[1] / N_COMM;
    const int D        = in_sizes[0] / B;
    const int N_ACTIVE = in_sizes[7];

    float* out_msgs  = (float*)d_out;
    float* out_nodes = out_msgs + (size_t)B * M * D;
    float* out_ts    = out_nodes + (size_t)B * M;

    (void)d_ws; (void)ws_size; (void)n_in; (void)out_size; (void)M; (void)D;

    topk_main_spec<<<B, 256, 0, stream>>>(
        unique_message, member_score, timestamps, nodes,
        node2community, community2node, member_num,
        community_index, N_ACTIVE,
        out_msgs, out_nodes, out_ts);
}